// Round 1
// 768.536 us; speedup vs baseline: 1.0380x; 1.0380x over previous
//
#include <hip/hip_runtime.h>

// Depth-dependent circle-of-confusion box-average, left/right views.
// Gather form: dest (Y,X) left view sums sources with |Y-y|<=R, 0<=x-X<=2R,
// where R = floor(depth) in 0..7. Key identity (R integer-valued):
//   [R >= hdx]*[R >= ady] = [R >= max(ady,hdx)] = sat01(R + 1 - max(ady,hdx))
// With sy/adx/j fully unrolled, max(ady,hdx) is a compile-time constant ->
// ONE clamped add per (tap, j, view), and the 12/72 (sy,j) pairs with
// ady > RMAX (provably zero weight) are eliminated at compile time.
// Taps sharing the same max across j (hdx >= all live ady) CSE to one sat.

constexpr int Hh = 1024, Ww = 1024, Bb = 8, Cc = 3;
constexpr int RMAX = 7;                   // depth in [0,8)
constexpr int TW = 64, TH = 16, LJ = 4;   // dest tile 64x16, 4 Y-dests/thread
constexpr int HX = 2 * RMAX;              // 14
constexpr int HY = RMAX;                  // 7
constexpr int WCOLS = TW + 2 * HX;        // 92
constexpr int WROWS = TH + 2 * HY;        // 30

__device__ __forceinline__ float sat01(float x) {
  return fminf(fmaxf(x, 0.0f), 1.0f);     // folds to v_add_f32 with clamp
}

__global__ __launch_bounds__(256)
void coc_gather(const float* __restrict__ img, const float* __restrict__ dep,
                float* __restrict__ out) {
  __shared__ float4 tile[WROWS * WCOLS];  // (r,g,b,R) ; R=floor(depth), 44160 B
  const int tx = threadIdx.x;             // 0..63 (dest X within tile)
  const int ty = threadIdx.y;             // 0..3
  const int tid = ty * 64 + tx;
  const int X0 = blockIdx.x * TW;
  const int Y0 = blockIdx.y * TH;
  const int b  = blockIdx.z;
  const size_t plane = (size_t)Hh * Ww;

  const float* db = dep + (size_t)b * plane;
  const float* ib = img + (size_t)b * Cc * plane;

  // ---- stage source window; OOB sentinel R=-1 makes all weights 0
  for (int idx = tid; idx < WROWS * WCOLS; idx += 256) {
    int lr = idx / WCOLS;
    int lc = idx - lr * WCOLS;
    int gy = Y0 - HY + lr;
    int gx = X0 - HX + lc;
    float4 v = make_float4(0.f, 0.f, 0.f, -1.f);
    if ((unsigned)gy < (unsigned)Hh && (unsigned)gx < (unsigned)Ww) {
      size_t p = (size_t)gy * Ww + gx;
      v.x = ib[p];
      v.y = ib[plane + p];
      v.z = ib[2 * plane + p];
      v.w = floorf(db[p]);                // pre-floor: integer-valued R
    }
    tile[idx] = v;
  }
  __syncthreads();

  float4 aL[LJ], aR[LJ];                  // (cnt, r, g, b) per dest row
  #pragma unroll
  for (int j = 0; j < LJ; ++j) {
    aL[j] = make_float4(0.f, 0.f, 0.f, 0.f);
    aR[j] = make_float4(0.f, 0.f, 0.f, 0.f);
  }

  const int lbase = ty * LJ;              // dest rows: Y0 + lbase + j
  #pragma unroll
  for (int sy = 0; sy < LJ + 2 * HY; ++sy) {        // 18 source rows, unrolled
    const float4* row = &tile[(lbase + sy) * WCOLS + tx + HX];  // dx = 0
    #pragma unroll
    for (int adx = 0; adx <= HX; ++adx) {           // 15 taps, mirrored views
      const int hdx = (adx + 1) >> 1;               // ceil(adx/2), 0..7
      const float4 sL = row[adx];     // left view  (dx = +adx)
      const float4 sR = row[-adx];    // right view (dx = -adx)
      #pragma unroll
      for (int j = 0; j < LJ; ++j) {
        const int dy = sy - HY - j;
        const int ady = dy < 0 ? -dy : dy;
        if (ady > RMAX) continue;     // compile-time dead: weight always 0
        const int m = ady > hdx ? ady : hdx;        // compile-time threshold
        const float c = 1.0f - (float)m;
        // single fused weight: [R >= max(ady,hdx)]; CSE merges equal-c sats
        const float wL = sat01(sL.w + c);
        const float wR = sat01(sR.w + c);
        aL[j].x += wL;
        aL[j].y = fmaf(wL, sL.x, aL[j].y);
        aL[j].z = fmaf(wL, sL.y, aL[j].z);
        aL[j].w = fmaf(wL, sL.z, aL[j].w);
        aR[j].x += wR;
        aR[j].y = fmaf(wR, sR.x, aR[j].y);
        aR[j].z = fmaf(wR, sR.y, aR[j].z);
        aR[j].w = fmaf(wR, sR.z, aR[j].w);
      }
    }
  }

  float* outL = out + (size_t)b * Cc * plane;
  float* outR = out + (size_t)(Bb + b) * Cc * plane;
  #pragma unroll
  for (int j = 0; j < LJ; ++j) {
    int Y = Y0 + lbase + j;
    size_t p = (size_t)Y * Ww + (X0 + tx);
    float invL = 1.0f / fmaxf(aL[j].x, 1.0f);
    float invR = 1.0f / fmaxf(aR[j].x, 1.0f);
    outL[p]             = fminf(fmaxf(aL[j].y * invL, 0.f), 1.f);
    outL[plane + p]     = fminf(fmaxf(aL[j].z * invL, 0.f), 1.f);
    outL[2 * plane + p] = fminf(fmaxf(aL[j].w * invL, 0.f), 1.f);
    outR[p]             = fminf(fmaxf(aR[j].y * invR, 0.f), 1.f);
    outR[plane + p]     = fminf(fmaxf(aR[j].z * invR, 0.f), 1.f);
    outR[2 * plane + p] = fminf(fmaxf(aR[j].w * invR, 0.f), 1.f);
  }
}

extern "C" void kernel_launch(void* const* d_in, const int* in_sizes, int n_in,
                              void* d_out, int out_size, void* d_ws, size_t ws_size,
                              hipStream_t stream) {
  const float* img = (const float*)d_in[0];   // (8,3,1024,1024) f32
  const float* dep = (const float*)d_in[1];   // (8,1024,1024) f32
  float* out = (float*)d_out;                 // left then right
  dim3 grid(Ww / TW, Hh / TH, Bb);            // 8192 blocks
  dim3 block(64, 4, 1);
  hipLaunchKernelGGL(coc_gather, grid, block, 0, stream, img, dep, out);
}

// Round 2
// 733.712 us; speedup vs baseline: 1.0873x; 1.0475x over previous
//
#include <hip/hip_runtime.h>

// Depth-dependent circle-of-confusion box-average, left/right views.
// Gather form: dest (Y,X) left view sums sources with |Y-y|<=R, 0<=x-X<=2R,
// where R = floor(depth) in 0..7. Key identity (R integer-valued):
//   [R >= hdx]*[R >= ady] = [R >= max(ady,hdx)] = sat01(R + 1 - max(ady,hdx))
// R2 change: LDS texels stored as fp16 (r,g,b,R) -> ds_read_b64 instead of
// b128 (halves LDS-pipe cycles, the co-bottleneck with VALU), and LDS/block
// drops 44.2->22.1 KB (3->7 blocks/CU) so DS and VALU issue from different
// waves can overlap instead of serializing. Accumulation stays f32 via
// v_fma_mix_f32 (f16 srcs); weights/counts exact (R, thresholds integral).

typedef _Float16 h4 __attribute__((ext_vector_type(4)));

constexpr int Hh = 1024, Ww = 1024, Bb = 8, Cc = 3;
constexpr int RMAX = 7;                   // depth in [0,8)
constexpr int TW = 64, TH = 16, LJ = 4;   // dest tile 64x16, 4 Y-dests/thread
constexpr int HX = 2 * RMAX;              // 14
constexpr int HY = RMAX;                  // 7
constexpr int WCOLS = TW + 2 * HX;        // 92
constexpr int WROWS = TH + 2 * HY;        // 30

__device__ __forceinline__ float sat01(float x) {
  return fminf(fmaxf(x, 0.0f), 1.0f);     // folds to clamp modifier
}

__global__ __launch_bounds__(256)
void coc_gather(const float* __restrict__ img, const float* __restrict__ dep,
                float* __restrict__ out) {
  __shared__ h4 tile[WROWS * WCOLS];      // (r,g,b,R) fp16 ; 22080 B
  const int tx = threadIdx.x;             // 0..63 (dest X within tile)
  const int ty = threadIdx.y;             // 0..3
  const int tid = ty * 64 + tx;
  const int X0 = blockIdx.x * TW;
  const int Y0 = blockIdx.y * TH;
  const int b  = blockIdx.z;
  const size_t plane = (size_t)Hh * Ww;

  const float* db = dep + (size_t)b * plane;
  const float* ib = img + (size_t)b * Cc * plane;

  // ---- stage source window; OOB sentinel R=-1 makes all weights 0
  for (int idx = tid; idx < WROWS * WCOLS; idx += 256) {
    int lr = idx / WCOLS;
    int lc = idx - lr * WCOLS;
    int gy = Y0 - HY + lr;
    int gx = X0 - HX + lc;
    h4 v = {(_Float16)0.f, (_Float16)0.f, (_Float16)0.f, (_Float16)-1.f};
    if ((unsigned)gy < (unsigned)Hh && (unsigned)gx < (unsigned)Ww) {
      size_t p = (size_t)gy * Ww + gx;
      v.x = (_Float16)ib[p];
      v.y = (_Float16)ib[plane + p];
      v.z = (_Float16)ib[2 * plane + p];
      v.w = (_Float16)floorf(db[p]);      // integer-valued R, exact in fp16
    }
    tile[idx] = v;
  }
  __syncthreads();

  float4 aL[LJ], aR[LJ];                  // (cnt, r, g, b) per dest row, f32
  #pragma unroll
  for (int j = 0; j < LJ; ++j) {
    aL[j] = make_float4(0.f, 0.f, 0.f, 0.f);
    aR[j] = make_float4(0.f, 0.f, 0.f, 0.f);
  }

  const int lbase = ty * LJ;              // dest rows: Y0 + lbase + j
  #pragma unroll
  for (int sy = 0; sy < LJ + 2 * HY; ++sy) {        // 18 source rows, unrolled
    const h4* row = &tile[(lbase + sy) * WCOLS + tx + HX];  // dx = 0
    #pragma unroll
    for (int adx = 0; adx <= HX; ++adx) {           // 15 taps, mirrored views
      const int hdx = (adx + 1) >> 1;               // ceil(adx/2), 0..7
      const h4 sL = row[adx];     // left view  (dx = +adx)
      const h4 sR = row[-adx];    // right view (dx = -adx)
      #pragma unroll
      for (int j = 0; j < LJ; ++j) {
        const int dy = sy - HY - j;
        const int ady = dy < 0 ? -dy : dy;
        if (ady > RMAX) continue;     // compile-time dead: weight always 0
        const int m = ady > hdx ? ady : hdx;        // compile-time threshold
        const float c = 1.0f - (float)m;
        // single fused weight: [R >= max(ady,hdx)]; CSE merges equal-c sats
        const float wL = sat01((float)sL.w + c);
        const float wR = sat01((float)sR.w + c);
        aL[j].x += wL;
        aL[j].y = fmaf(wL, (float)sL.x, aL[j].y);   // v_fma_mix_f32
        aL[j].z = fmaf(wL, (float)sL.y, aL[j].z);
        aL[j].w = fmaf(wL, (float)sL.z, aL[j].w);
        aR[j].x += wR;
        aR[j].y = fmaf(wR, (float)sR.x, aR[j].y);
        aR[j].z = fmaf(wR, (float)sR.y, aR[j].z);
        aR[j].w = fmaf(wR, (float)sR.z, aR[j].w);
      }
    }
  }

  float* outL = out + (size_t)b * Cc * plane;
  float* outR = out + (size_t)(Bb + b) * Cc * plane;
  #pragma unroll
  for (int j = 0; j < LJ; ++j) {
    int Y = Y0 + lbase + j;
    size_t p = (size_t)Y * Ww + (X0 + tx);
    float invL = 1.0f / fmaxf(aL[j].x, 1.0f);
    float invR = 1.0f / fmaxf(aR[j].x, 1.0f);
    outL[p]             = fminf(fmaxf(aL[j].y * invL, 0.f), 1.f);
    outL[plane + p]     = fminf(fmaxf(aL[j].z * invL, 0.f), 1.f);
    outL[2 * plane + p] = fminf(fmaxf(aL[j].w * invL, 0.f), 1.f);
    outR[p]             = fminf(fmaxf(aR[j].y * invR, 0.f), 1.f);
    outR[plane + p]     = fminf(fmaxf(aR[j].z * invR, 0.f), 1.f);
    outR[2 * plane + p] = fminf(fmaxf(aR[j].w * invR, 0.f), 1.f);
  }
}

extern "C" void kernel_launch(void* const* d_in, const int* in_sizes, int n_in,
                              void* d_out, int out_size, void* d_ws, size_t ws_size,
                              hipStream_t stream) {
  const float* img = (const float*)d_in[0];   // (8,3,1024,1024) f32
  const float* dep = (const float*)d_in[1];   // (8,1024,1024) f32
  float* out = (float*)d_out;                 // left then right
  dim3 grid(Ww / TW, Hh / TH, Bb);            // 8192 blocks
  dim3 block(64, 4, 1);
  hipLaunchKernelGGL(coc_gather, grid, block, 0, stream, img, dep, out);
}